// Round 7
// baseline (157.966 us; speedup 1.0000x reference)
//
#include <hip/hip_runtime.h>

// CostConcatenation: out[b, dd, h, w, :] = valid ? concat(left[b,h,w,:], right[b,h,w-d,:]) : 0
//   d = dd - 48, valid iff 0 <= w-d < 256 (both halves zeroed when invalid).
// left/right [2,64,256,32] f32; out [2,96,64,256,64] f32 (805 MB written once).
//
// R7 theory: R4 (149us, 5.4 TB/s) trails the pure-store fill (6.8 TB/s) because
// every store sources ds_read (lgkmcnt stalls) at only 8 waves/CU. Fix:
//  - wave-uniform split by output half: LEFT waves keep their 16 k-invariant f4
//    in VGPRs -> main loop is cmp+cndmask+store, ZERO reads, ZERO waits (fill-like);
//    RIGHT waves read the right row from LDS (address-cndmask to a zero slot).
//  - LDS shrinks to the right row only (32.9 KB) -> 4 blocks/CU, 16 waves/CU.
//  - grid 1024 = hb(128) x ddgroup(8), 12 disparities per block.
// Paired left/right waves fill complementary 128B segments of each 4KB granule:
// same number of fully-covered 128B transactions as dense 1KB wave stores.

typedef float f4 __attribute__((ext_vector_type(4)));

#define DD_STRIDE 262144   // f4 per disparity slice (64*256*16)

__global__ __launch_bounds__(256) void cost_concat_kernel(
    const f4* __restrict__ left4,
    const f4* __restrict__ right4,
    f4* __restrict__ out4)
{
    __shared__ f4 ldsR[2056];          // [0,2048) right row | [2048,2056) zero slot

    const int t   = threadIdx.x;
    const int bid = blockIdx.x;        // 1024 = hb(128) * g(8)
    const int g   = bid & 7;           // dd group: dd in [g*12, g*12+12)
    const int hb  = bid >> 3;          // b*64 + h
    const int dd0 = g * 12;
    const int rowBase = hb * 2048;     // f4 base of input row (256 w * 8 f4)

    // ---- stage right row (all threads, coalesced) + zero slot ----
    #pragma unroll
    for (int i = 0; i < 8; ++i)
        ldsR[i * 256 + t] = right4[rowBase + i * 256 + t];
    if (t < 8) ldsR[2048 + t] = (f4){0.f, 0.f, 0.f, 0.f};

    const int lane = t & 63;
    const int wv   = t >> 6;           // wave 0..3
    const int s    = wv & 1;           // 0 = left-half wave, 1 = right-half wave
    const int pg   = wv >> 1;          // pixel sub-group
    const int cc   = lane & 7;         // f4 within the 32-channel half
    const int px   = pg * 8 + (lane >> 3);   // pixel within 16-px granule, 0..15

    // ---- left waves: 16 k-invariant f4 into registers (coalesced 1KB/wave/j) ----
    f4 Lreg[16];
    if (s == 0) {
        #pragma unroll
        for (int j = 0; j < 16; ++j)
            Lreg[j] = left4[rowBase + (j * 16 + px) * 8 + cc];
    }

    __syncthreads();

    const int b = hb >> 6, h = hb & 63;
    f4* op0 = out4 + (size_t)b * 25165824 + (size_t)dd0 * DD_STRIDE
                   + (size_t)h * 4096 + (size_t)(px * 16 + s * 8 + cc);
    const f4 z = (f4){0.f, 0.f, 0.f, 0.f};

    if (s == 0) {
        // wait-free half: registers -> stores
        for (int k = 0; k < 12; ++k) {
            const int d = dd0 + k - 48;
            f4* op = op0 + (size_t)k * DD_STRIDE;
            #pragma unroll
            for (int j = 0; j < 16; ++j) {
                const int w = j * 16 + px;
                const bool valid = (unsigned)(w - d) < 256u;
                op[j * 256] = valid ? Lreg[j] : z;
            }
        }
    } else {
        // LDS half: one address-cndmask, ds_read_b128 -> store
        for (int k = 0; k < 12; ++k) {
            const int d = dd0 + k - 48;
            f4* op = op0 + (size_t)k * DD_STRIDE;
            #pragma unroll
            for (int j = 0; j < 16; ++j) {
                const int idx = j * 16 + px - d;          // right-image column
                const bool valid = (unsigned)idx < 256u;
                const int la = valid ? (idx * 8 + cc) : (2048 + cc);
                op[j * 256] = ldsR[la];
            }
        }
    }
}

extern "C" void kernel_launch(void* const* d_in, const int* in_sizes, int n_in,
                              void* d_out, int out_size, void* d_ws, size_t ws_size,
                              hipStream_t stream) {
    const f4* left4  = (const f4*)d_in[0];
    const f4* right4 = (const f4*)d_in[1];
    f4* out4 = (f4*)d_out;

    // 1024 blocks x 256 thr; 32.9 KB LDS -> 4 blocks/CU, 16 waves/CU.
    cost_concat_kernel<<<1024, 256, 0, stream>>>(left4, right4, out4);
}

// Round 8
// 150.597 us; speedup vs baseline: 1.0489x; 1.0489x over previous
//
#include <hip/hip_runtime.h>

// CostConcatenation: out[b, dd, h, w, :] = valid ? concat(left[b,h,w,:], right[b,h,w-d,:]) : 0
//   d = dd - 48, valid iff 0 <= w-d < 256 (both halves zeroed when invalid).
// left/right [2,64,256,32] f32; out [2,96,64,256,64] f32 (805 MB written once).
//
// R8 = R4's dense-store LDS structure at 4x the occupancy:
//  - block = (hb, ddgroup(4), whalf(2)): 1024 blocks x 512 thr, ALL resident
//    (4 blocks/CU, 32 waves/CU vs R4's 8) -> ds_read lgkmcnt stalls covered.
//  - LDS 36 KB: left half-row [w0,w0+128) + right window of 152 cols
//    ZERO-PADDED outside [0,256) + a zero slot -> hot loop has ONE address
//    cndmask, no data selects, ds_read_b128 feeds the store directly.
//  - stores stay dense: 512 thr x 16 B = 8 KB contiguous per (k,j) step
//    (R7 showed segmented stores cost ~6%). Plain stores (NT falsified R5).

typedef float f4 __attribute__((ext_vector_type(4)));

#define DD_STRIDE 262144   // f4 per disparity slice (64*256*16)

__global__ __launch_bounds__(512) void cost_concat_kernel(
    const f4* __restrict__ left4,
    const f4* __restrict__ right4,
    f4* __restrict__ out4)
{
    __shared__ f4 lds[2248];  // [0,1024) left half | [1024,2240) right window | [2240,2248) zero

    const int t   = threadIdx.x;          // 0..511
    const int bid = blockIdx.x;           // 1024 = hb(128) * g(4) * wh(2)
    const int wh  = bid & 1;
    const int g   = (bid >> 1) & 3;       // dd group: dd in [g*24, g*24+24)
    const int hb  = bid >> 3;             // b*64 + h
    const int w0  = wh << 7;
    const int dd0 = g * 24;
    const int rowBase = hb * 2048;        // f4 base of input row (256 w * 8 f4)

    // ---- stage left half-row: cols [w0, w0+128) ----
    #pragma unroll
    for (int i = 0; i < 2; ++i)
        lds[i * 512 + t] = left4[rowBase + w0 * 8 + i * 512 + t];

    // ---- stage right window: 152 cols [c_lo, c_lo+152), zeros outside [0,256) ----
    // needed idx range: [w0-dd0+25, w0-dd0+175]  (151 cols; stage 152)
    const int c_lo = w0 - dd0 + 25;
    #pragma unroll
    for (int i = 0; i < 3; ++i) {
        const int q = i * 512 + t;        // [0,1536)
        if (q < 1216) {
            const int col = c_lo + (q >> 3);
            f4 v = (f4){0.f, 0.f, 0.f, 0.f};
            if ((unsigned)col < 256u)
                v = right4[rowBase + col * 8 + (q & 7)];
            lds[1024 + q] = v;
        }
    }
    if (t < 8) lds[2240 + t] = (f4){0.f, 0.f, 0.f, 0.f};
    __syncthreads();

    const int c4 = t & 15;                // f4 within the 64-channel pixel
    const int wb = t >> 4;                // pixel within 32-px granule
    const int cc = c4 & 7;
    const bool isLeft = c4 < 8;

    const int Z = 2240 * 16;              // byte addr of zero slot
    // left lane  (j): ((j*32+wb)*8 + cc)*16, k-invariant
    // right lane (j,k): (1024 + p*8 + cc)*16, p = j*32+wb+23-k  (in [0,150])
    int addr[4], idx0[4];
    #pragma unroll
    for (int j = 0; j < 4; ++j) {
        addr[j] = isLeft ? ((j * 32 + wb) * 128 + cc * 16)
                         : (16384 + (j * 32 + wb + 23) * 128 + cc * 16);
        idx0[j] = j * 32 + wb + w0 - dd0 + 48;   // idx at k=0; valid iff [0,256)
    }
    const int dec = isLeft ? 0 : 128;

    const int b = hb >> 6, h = hb & 63;
    f4* orow = out4 + (size_t)b * 25165824 + (size_t)dd0 * DD_STRIDE
                    + (size_t)h * 4096 + (size_t)(w0 * 16);
    const char* lb = (const char*)lds;

    for (int k = 0; k < 24; ++k) {
        f4* op = orow + (size_t)k * DD_STRIDE;
        #pragma unroll
        for (int j = 0; j < 4; ++j) {
            const int idx = idx0[j] - k;
            const int sel = ((unsigned)idx < 256u) ? addr[j] : Z;
            f4 v = *(const f4*)(lb + sel);
            op[j * 512 + t] = v;          // 8 KB dense per (k,j)
        }
        #pragma unroll
        for (int j = 0; j < 4; ++j) addr[j] -= dec;
    }
}

extern "C" void kernel_launch(void* const* d_in, const int* in_sizes, int n_in,
                              void* d_out, int out_size, void* d_ws, size_t ws_size,
                              hipStream_t stream) {
    const f4* left4  = (const f4*)d_in[0];
    const f4* right4 = (const f4*)d_in[1];
    f4* out4 = (f4*)d_out;

    // 1024 blocks x 512 thr, 36 KB LDS -> 4 blocks/CU, 32 waves/CU, all resident.
    cost_concat_kernel<<<1024, 512, 0, stream>>>(left4, right4, out4);
}